// Round 15
// baseline (97.981 us; speedup 1.0000x reference)
//
#include <hip/hip_runtime.h>

typedef __attribute__((ext_vector_type(8))) short bf16x8;
typedef __attribute__((ext_vector_type(4))) float f32x4;
typedef __attribute__((ext_vector_type(4))) int i32x4;
typedef __attribute__((ext_vector_type(4))) float float4v;

#define MFMA16(a, b, c) __builtin_amdgcn_mfma_f32_16x16x32_bf16((a), (b), (c), 0, 0, 0)

__device__ __forceinline__ unsigned short f2bf(float f) {
    unsigned u = __builtin_bit_cast(unsigned, f);
    u += 0x7fffu + ((u >> 16) & 1u);
    return (unsigned short)(u >> 16);
}
__device__ __forceinline__ float bf2f(unsigned short s) {
    unsigned u = ((unsigned)s) << 16;
    return __builtin_bit_cast(float, u);
}
__device__ __forceinline__ int pkbf(float a, float b) {
    return (int)f2bf(a) | ((int)f2bf(b) << 16);
}

// LDS map (bytes), total 152064:
//   [0, 131072)       blk^T bf16 [m=512][c=128], byte = (m*256 + 2c) ^ (((m>>2)&7)<<4)
//                     then (chunk ck): Vhat bf16, byte = ck*32768 + c*256 + (2*(mk&127) ^ ((c&7)<<4))
//                     then (after P4): O bf16 [c=128][nql=128], byte = c*256 + (2*nql ^ ((c&7)<<4))
//   [131072, 151552)  PADDED 40 B rows (conflict-free b128 reads):
//                     per-wave qhat scratch (wv*2560 + row*40 + 2d), then
//                     Khat bf16: mk*40 + 2d  (wave wv's keys = its own scratch slice)
//   [151552, 152064)  l[128] f32 softmax denominators (wg-local queries)
#define KOFF 131072
#define LOFF 151552

// ---------------------------------------------------------------------------
// Wave-specialized battn: 256 wgs x 1024 threads (16 waves), 4 wgs/p, XCD-
// co-located. Staging = patch-based (b128 LDS writes, conflict-free).
// P1/P2/P4: waves 0..7. P3: all 16 waves (chunk-split). Epilogue: all 16
// waves, residuals prefetched right after B3 (hide under P4).
// Runs AFTER the SDMA memcpy (out = x everywhere).
// ---------------------------------------------------------------------------
__global__ __launch_bounds__(1024, 1) void battn_kernel(
    const float* __restrict__ x,
    const float* __restrict__ Wq, const float* __restrict__ bq,
    const float* __restrict__ Wk, const float* __restrict__ bk,
    const float* __restrict__ Wv, const float* __restrict__ bv,
    const float* __restrict__ gamma, float* __restrict__ out)
{
    __shared__ __attribute__((aligned(128))) char smem[152064];
    const int tid = threadIdx.x;
    const int bid = blockIdx.x;
    const int p  = ((bid & 7) << 3) | (bid >> 5);   // 64 blocks, 4 wgs/p per XCD
    const int qq = (bid >> 3) & 3;                  // query quarter
    const int ib = p >> 3, jb = p & 7;
    const int vbase = ib * 32768 + jb * 512 + ib * 8;
    const int lane = tid & 63, wv = tid >> 6;       // 16 waves
    const int g = lane >> 4, c15 = lane & 15;
    const f32x4 zacc = {0.f, 0.f, 0.f, 0.f};
    const bf16x8 zfrag = (bf16x8)(short)0;

    // phase 0: patch-based staging. 2048 patches of 4m x 8c; thread t owns
    // patches t and t+1024. 8 scattered 16 B loads -> 4 conflict-free b128
    // LDS writes per patch (16 consecutive lanes tile a full 256 B row).
    {
        int pi0 = tid, pi1 = tid + 1024;
        int c0a = (pi0 & 15) * 8, m0a = (pi0 >> 4) * 4;
        int c0b = (pi1 & 15) * 8, m0b = (pi1 >> 4) * 4;
        int voxa = ((m0a >> 6) << 12) + (((m0a >> 3) & 7) << 6) + (m0a & 7);
        int voxb = ((m0b >> 6) << 12) + (((m0b >> 3) & 7) << 6) + (m0b & 7);
        float4v t0[8], t1[8];
        #pragma unroll
        for (int j = 0; j < 8; ++j)
            t0[j] = *(const float4v*)(x + (c0a + j) * 262144 + vbase + voxa);
        #pragma unroll
        for (int j = 0; j < 8; ++j)
            t1[j] = *(const float4v*)(x + (c0b + j) * 262144 + vbase + voxb);
        #pragma unroll
        for (int r = 0; r < 4; ++r) {
            int m = m0a + r;
            i32x4 w = { pkbf(t0[0][r], t0[1][r]), pkbf(t0[2][r], t0[3][r]),
                        pkbf(t0[4][r], t0[5][r]), pkbf(t0[6][r], t0[7][r]) };
            *(i32x4*)(smem + ((m * 256 + 2 * c0a) ^ (((m >> 2) & 7) << 4))) = w;
        }
        #pragma unroll
        for (int r = 0; r < 4; ++r) {
            int m = m0b + r;
            i32x4 w = { pkbf(t1[0][r], t1[1][r]), pkbf(t1[2][r], t1[3][r]),
                        pkbf(t1[4][r], t1[5][r]), pkbf(t1[6][r], t1[7][r]) };
            *(i32x4*)(smem + ((m * 256 + 2 * c0b) ^ (((m >> 2) & 7) << 4))) = w;
        }
    }

    // weight fragments: wvf for ALL waves (wave wv handles channels (wv&7)*16..);
    // wqf/wkf only for compute waves 0..7.
    bf16x8 wqf[4], wkf[4], wvf[4];
    float bqv = 0.f, bkv = 0.f;
    #pragma unroll
    for (int ks = 0; ks < 4; ++ks) {
        const float4v* sv = (const float4v*)(Wv + ((wv & 7) * 16 + c15) * 128 + ks * 32 + g * 8);
        float4v v0 = sv[0], v1 = sv[1];
        #pragma unroll
        for (int e = 0; e < 4; ++e) {
            wvf[ks][e] = (short)f2bf(v0[e]); wvf[ks][4 + e] = (short)f2bf(v1[e]);
        }
        if (wv < 8) {
            const float4v* sq = (const float4v*)(Wq + c15 * 128 + ks * 32 + g * 8);
            const float4v* sk = (const float4v*)(Wk + c15 * 128 + ks * 32 + g * 8);
            float4v q0 = sq[0], q1 = sq[1];
            float4v k0 = sk[0], k1 = sk[1];
            #pragma unroll
            for (int e = 0; e < 4; ++e) {
                wqf[ks][e] = (short)f2bf(q0[e]); wqf[ks][4 + e] = (short)f2bf(q1[e]);
                wkf[ks][e] = (short)f2bf(k0[e]); wkf[ks][4 + e] = (short)f2bf(k1[e]);
            }
        }
    }
    if (wv < 8) { bqv = bq[c15]; bkv = bk[c15]; }

    __syncthreads();   // B1: blkT staged

    bf16x8 qf = zfrag;
    if (wv < 8) {
        // P1: qhat for this wave's 16 queries -> padded scratch (40 B rows)
        {
            f32x4 acc = zacc;
            int mrow = qq * 128 + wv * 16 + c15;
            int sw = ((mrow >> 2) & 7) << 4;
            #pragma unroll
            for (int ks = 0; ks < 4; ++ks) {
                bf16x8 af = *(const bf16x8*)(smem + ((mrow * 256 + ks * 64 + g * 16) ^ sw));
                acc = MFMA16(af, wqf[ks], acc);
            }
            #pragma unroll
            for (int r = 0; r < 4; ++r)
                *(unsigned short*)(smem + KOFF + wv * 2560 + (g * 4 + r) * 40 + 2 * c15) = f2bf(acc[r] + bqv);
        }
        if (g < 2) qf = *(const bf16x8*)(smem + KOFF + wv * 2560 + c15 * 40 + g * 16);

        // P2: Khat[mk] (40 B rows) for this wave's 64 keys (own scratch slice)
        #pragma unroll
        for (int qi = 0; qi < 4; ++qi) {
            f32x4 acc = zacc;
            int mrow = wv * 64 + qi * 16 + c15;
            int sw = ((mrow >> 2) & 7) << 4;
            #pragma unroll
            for (int ks = 0; ks < 4; ++ks) {
                bf16x8 af = *(const bf16x8*)(smem + ((mrow * 256 + ks * 64 + g * 16) ^ sw));
                acc = MFMA16(af, wkf[ks], acc);
            }
            #pragma unroll
            for (int r = 0; r < 4; ++r) {
                int mk = wv * 64 + qi * 16 + g * 4 + r;
                *(unsigned short*)(smem + KOFF + mk * 40 + 2 * c15) = f2bf(acc[r] + bkv);
            }
        }
    }

    // P3: Vhat, ALL 16 waves. Waves 0..7: chunks 0-1; waves 8..15: chunks 2-3.
    // Each wave: its 16 channels x 256 keys. Read-all, one barrier, write-all.
    {
        const int ck0 = (wv >> 3) * 2;
        f32x4 vacc[2][8];
        #pragma unroll
        for (int cc = 0; cc < 2; ++cc)
            #pragma unroll
            for (int mt = 0; mt < 8; ++mt) {
                vacc[cc][mt] = zacc;
                int mrow = (ck0 + cc) * 128 + mt * 16 + c15;
                int sw = ((mrow >> 2) & 7) << 4;
                #pragma unroll
                for (int ks = 0; ks < 4; ++ks) {
                    bf16x8 bf = *(const bf16x8*)(smem + ((mrow * 256 + ks * 64 + g * 16) ^ sw));
                    vacc[cc][mt] = MFMA16(wvf[ks], bf, vacc[cc][mt]);
                }
            }
        __syncthreads();   // all blkT reads (P1,P2,P3) done everywhere
        #pragma unroll
        for (int cc = 0; cc < 2; ++cc)
            #pragma unroll
            for (int mt = 0; mt < 8; ++mt)
                #pragma unroll
                for (int r = 0; r < 4; ++r) {
                    int c_out = (wv & 7) * 16 + g * 4 + r;
                    int mkl = mt * 16 + c15;
                    *(unsigned short*)(smem + (ck0 + cc) * 32768 + c_out * 256 +
                                       ((2 * mkl) ^ ((c_out & 7) << 4))) = f2bf(vacc[cc][mt][r]);
                }
    }
    __syncthreads();   // B3: Vhat + Khat visible

    // epilogue prefetch (ALL threads): 16 residual reads; complete during P4.
    const int q128 = tid & 127;
    const int h8 = tid >> 7;                        // 0..7 -> 16 channels each
    float xv[16];
    int go_e;
    {
        int nq_e = qq * 128 + q128;
        int vox_e = ((nq_e >> 6) << 12) + (((nq_e >> 3) & 7) << 6) + (nq_e & 7);
        go_e = vbase + vox_e;
        #pragma unroll
        for (int i = 0; i < 16; ++i)
            xv[i] = out[(h8 * 16 + i) * 262144 + go_e];   // = x (memcpy'd), hot
    }

    // P4: barrier-free key-tile loop (waves 0..7). O[16q][128c] per wave.
    if (wv < 8) {
        f32x4 o[8];
        #pragma unroll
        for (int ci = 0; ci < 8; ++ci) o[ci] = zacc;
        float lsum = 0.f;

        for (int kt = 0; kt < 16; ++kt) {
            int mk0 = kt * 32;
            bf16x8 ka[2];
            #pragma unroll
            for (int ki = 0; ki < 2; ++ki) {
                bf16x8 v = zfrag;
                if (g < 2) v = *(const bf16x8*)(smem + KOFF + (mk0 + ki * 16 + c15) * 40 + g * 16);
                ka[ki] = v;
            }

            f32x4 s0 = MFMA16(ka[0], qf, zacc);
            f32x4 s1 = MFMA16(ka[1], qf, zacc);
            float e00 = __expf(s0[0]), e01 = __expf(s0[1]), e02 = __expf(s0[2]), e03 = __expf(s0[3]);
            float e10 = __expf(s1[0]), e11 = __expf(s1[1]), e12 = __expf(s1[2]), e13 = __expf(s1[3]);
            lsum += (e00 + e01) + (e02 + e03) + ((e10 + e11) + (e12 + e13));
            int wA0 = pkbf(e00, e01), wB0 = pkbf(e02, e03);
            int wA1 = pkbf(e10, e11), wB1 = pkbf(e12, e13);
            int src1 = ((2 * g) & 3) * 16 + c15;
            int src2 = ((2 * g + 1) & 3) * 16 + c15;
            int sA0a = __shfl(wA0, src1, 64), sA1a = __shfl(wA1, src1, 64);
            int sB0a = __shfl(wB0, src1, 64), sB1a = __shfl(wB1, src1, 64);
            int sA0b = __shfl(wA0, src2, 64), sA1b = __shfl(wA1, src2, 64);
            int sB0b = __shfl(wB0, src2, 64), sB1b = __shfl(wB1, src2, 64);
            bool k1 = (g >= 2);
            i32x4 uu = { k1 ? sA1a : sA0a, k1 ? sB1a : sB0a,
                         k1 ? sA1b : sA0b, k1 ? sB1b : sB0b };
            bf16x8 pa = __builtin_bit_cast(bf16x8, uu);

            int ckbase = (mk0 >> 7) * 32768;
            int mklb = (2 * (mk0 & 127)) + 16 * g;
            #pragma unroll
            for (int ci = 0; ci < 8; ++ci) {
                int c = ci * 16 + c15;
                bf16x8 vb = *(const bf16x8*)(smem + ckbase + c * 256 + (mklb ^ ((c & 7) << 4)));
                o[ci] = MFMA16(pa, vb, o[ci]);
            }
        }

        // softmax denominators for this wave's 16 queries
        {
            float l = lsum;
            l += __shfl_xor(l, 16, 64);
            l += __shfl_xor(l, 32, 64);
            if (g == 0)
                *(float*)(smem + LOFF + (wv * 16 + c15) * 4) = l;
        }

        __syncthreads();   // B4: Vhat/Khat reads done, safe to overwrite with O

        #pragma unroll
        for (int ci = 0; ci < 8; ++ci)
            #pragma unroll
            for (int r = 0; r < 4; ++r) {
                int nql = wv * 16 + g * 4 + r;       // 0..127
                int c = ci * 16 + c15;
                *(unsigned short*)(smem + c * 256 + ((2 * nql) ^ ((c & 7) << 4))) = f2bf(o[ci][r]);
            }
        __syncthreads();   // B5: O visible
    } else {
        __syncthreads();   // B4
        __syncthreads();   // B5
    }

    // epilogue (ALL 16 waves, 16 channels/thread): out = gamma*(O/l+bv) + x
    {
        float gma = gamma[0];
        float invl = 1.0f / *(const float*)(smem + LOFF + q128 * 4);
        #pragma unroll
        for (int i = 0; i < 16; ++i) {
            int c = h8 * 16 + i;
            float ov = bf2f(*(const unsigned short*)(smem + c * 256 + ((2 * q128) ^ ((c & 7) << 4))));
            out[c * 262144 + go_e] = gma * (ov * invl + bv[c]) + xv[i];
        }
    }
}

extern "C" void kernel_launch(void* const* d_in, const int* in_sizes, int n_in,
                              void* d_out, int out_size, void* d_ws, size_t ws_size,
                              hipStream_t stream) {
    const float* x     = (const float*)d_in[0];
    const float* Wq    = (const float*)d_in[1];
    const float* bq    = (const float*)d_in[2];
    const float* Wk    = (const float*)d_in[3];
    const float* bk    = (const float*)d_in[4];
    const float* Wv    = (const float*)d_in[5];
    const float* bv    = (const float*)d_in[6];
    const float* gamma = (const float*)d_in[7];
    float* out = (float*)d_out;
    (void)in_sizes; (void)n_in; (void)out_size; (void)d_ws; (void)ws_size;

    // 1) SDMA copy: out = x everywhere (diagonal stale, overwritten below).
    hipMemcpyAsync(out, x, (size_t)out_size * sizeof(float),
                   hipMemcpyDeviceToDevice, stream);
    // 2) Wave-specialized diagonal attention (conflict-free LDS paths).
    battn_kernel<<<dim3(256), dim3(1024), 0, stream>>>(x, Wq, bq, Wk, bk, Wv, bv, gamma, out);
}

// Round 16
// 95.741 us; speedup vs baseline: 1.0234x; 1.0234x over previous
//
#include <hip/hip_runtime.h>

typedef __attribute__((ext_vector_type(8))) short bf16x8;
typedef __attribute__((ext_vector_type(4))) float f32x4;
typedef __attribute__((ext_vector_type(4))) int i32x4;
typedef __attribute__((ext_vector_type(4))) float float4v;

#define MFMA16(a, b, c) __builtin_amdgcn_mfma_f32_16x16x32_bf16((a), (b), (c), 0, 0, 0)

__device__ __forceinline__ unsigned short f2bf(float f) {
    unsigned u = __builtin_bit_cast(unsigned, f);
    u += 0x7fffu + ((u >> 16) & 1u);
    return (unsigned short)(u >> 16);
}
__device__ __forceinline__ float bf2f(unsigned short s) {
    unsigned u = ((unsigned)s) << 16;
    return __builtin_bit_cast(float, u);
}
__device__ __forceinline__ int pkbf(float a, float b) {
    return (int)f2bf(a) | ((int)f2bf(b) << 16);
}

// LDS map (bytes), total 147968 — identical to round 14.
#define KOFF 131072
#define LOFF 147456

// ---------------------------------------------------------------------------
// Round-14 base + ONLY the 16-wave P3/epilogue splits (A/B vs round 15):
//   - staging: round-14 pattern, ALL 16 waves
//   - P1/P2/P4 + O-write: waves 0..7 (byte-identical to round 14)
//   - P3: all 16 waves (waves 0..7 -> chunks 0-1, 8..15 -> chunks 2-3)
//   - epilogue: all 16 waves, 16 ch/thread, prefetched right after B3
// Runs AFTER the SDMA memcpy (out = x everywhere).
// ---------------------------------------------------------------------------
__global__ __launch_bounds__(1024, 1) void battn_kernel(
    const float* __restrict__ x,
    const float* __restrict__ Wq, const float* __restrict__ bq,
    const float* __restrict__ Wk, const float* __restrict__ bk,
    const float* __restrict__ Wv, const float* __restrict__ bv,
    const float* __restrict__ gamma, float* __restrict__ out)
{
    __shared__ __attribute__((aligned(128))) char smem[147968];
    const int tid = threadIdx.x;
    const int bid = blockIdx.x;
    const int p  = ((bid & 7) << 3) | (bid >> 5);   // 64 blocks, 4 wgs/p per XCD
    const int qq = (bid >> 3) & 3;                  // query quarter
    const int ib = p >> 3, jb = p & 7;
    const int vbase = ib * 32768 + jb * 512 + ib * 8;
    const int lane = tid & 63, wv = tid >> 6;       // 16 waves
    const int g = lane >> 4, c15 = lane & 15;
    const f32x4 zacc = {0.f, 0.f, 0.f, 0.f};
    const bf16x8 zfrag = (bf16x8)(short)0;

    // phase 0: stage FULL x block -> blk^T bf16 (swizzled). ALL 16 waves.
    // (round-14 pattern, byte-identical)
    #pragma unroll
    for (int b = 0; b < 2; ++b) {
        float4v t[8];
        #pragma unroll
        for (int j = 0; j < 8; ++j) {
            int ch = (b * 8 + j) * 1024 + tid;
            int c = ch >> 7;
            int m = (ch & 127) * 4;
            int vox = ((m >> 6) << 12) + (((m >> 3) & 7) << 6) + (m & 7);
            t[j] = *(const float4v*)(x + c * 262144 + vbase + vox);
        }
        #pragma unroll
        for (int j = 0; j < 8; ++j) {
            int ch = (b * 8 + j) * 1024 + tid;
            int c = ch >> 7;
            int m = (ch & 127) * 4;
            char* bp = smem + ((m * 256 + 2 * c) ^ (((m >> 2) & 7) << 4));
            *(unsigned short*)(bp)       = f2bf(t[j][0]);
            *(unsigned short*)(bp + 256) = f2bf(t[j][1]);
            *(unsigned short*)(bp + 512) = f2bf(t[j][2]);
            *(unsigned short*)(bp + 768) = f2bf(t[j][3]);
        }
    }

    // weight fragments: wvf for ALL waves (wave wv -> channels (wv&7)*16..);
    // wqf/wkf only for compute waves 0..7.
    bf16x8 wqf[4], wkf[4], wvf[4];
    float bqv = 0.f, bkv = 0.f;
    #pragma unroll
    for (int ks = 0; ks < 4; ++ks) {
        const float4v* sv = (const float4v*)(Wv + ((wv & 7) * 16 + c15) * 128 + ks * 32 + g * 8);
        float4v v0 = sv[0], v1 = sv[1];
        #pragma unroll
        for (int e = 0; e < 4; ++e) {
            wvf[ks][e] = (short)f2bf(v0[e]); wvf[ks][4 + e] = (short)f2bf(v1[e]);
        }
        if (wv < 8) {
            const float4v* sq = (const float4v*)(Wq + c15 * 128 + ks * 32 + g * 8);
            const float4v* sk = (const float4v*)(Wk + c15 * 128 + ks * 32 + g * 8);
            float4v q0 = sq[0], q1 = sq[1];
            float4v k0 = sk[0], k1 = sk[1];
            #pragma unroll
            for (int e = 0; e < 4; ++e) {
                wqf[ks][e] = (short)f2bf(q0[e]); wqf[ks][4 + e] = (short)f2bf(q1[e]);
                wkf[ks][e] = (short)f2bf(k0[e]); wkf[ks][4 + e] = (short)f2bf(k1[e]);
            }
        }
    }
    if (wv < 8) { bqv = bq[c15]; bkv = bk[c15]; }

    __syncthreads();   // B1: blkT staged

    bf16x8 qf = zfrag;
    if (wv < 8) {
        // P1: qhat for this wave's 16 queries (tile qq*128 + wv*16), wave-local
        {
            f32x4 acc = zacc;
            int mrow = qq * 128 + wv * 16 + c15;
            int sw = ((mrow >> 2) & 7) << 4;
            #pragma unroll
            for (int ks = 0; ks < 4; ++ks) {
                bf16x8 af = *(const bf16x8*)(smem + ((mrow * 256 + ks * 64 + g * 16) ^ sw));
                acc = MFMA16(af, wqf[ks], acc);
            }
            #pragma unroll
            for (int r = 0; r < 4; ++r)
                *(unsigned short*)(smem + KOFF + wv * 2048 + (g * 4 + r) * 32 + 2 * c15) = f2bf(acc[r] + bqv);
        }
        if (g < 2) qf = *(const bf16x8*)(smem + KOFF + wv * 2048 + c15 * 32 + g * 16);

        // P2: Khat[mk][d] for this wave's 64 keys (overwrites own scratch slice)
        #pragma unroll
        for (int qi = 0; qi < 4; ++qi) {
            f32x4 acc = zacc;
            int mrow = wv * 64 + qi * 16 + c15;
            int sw = ((mrow >> 2) & 7) << 4;
            #pragma unroll
            for (int ks = 0; ks < 4; ++ks) {
                bf16x8 af = *(const bf16x8*)(smem + ((mrow * 256 + ks * 64 + g * 16) ^ sw));
                acc = MFMA16(af, wkf[ks], acc);
            }
            #pragma unroll
            for (int r = 0; r < 4; ++r) {
                int mk = wv * 64 + qi * 16 + g * 4 + r;
                *(unsigned short*)(smem + KOFF + mk * 32 + 2 * c15) = f2bf(acc[r] + bkv);
            }
        }
    }

    // P3: Vhat, ALL 16 waves. Waves 0..7: chunks 0-1; waves 8..15: chunks 2-3.
    // Each wave: its 16 channels x 256 keys. Read-all, one barrier, write-all.
    {
        const int ck0 = (wv >> 3) * 2;
        f32x4 vacc[2][8];
        #pragma unroll
        for (int cc = 0; cc < 2; ++cc)
            #pragma unroll
            for (int mt = 0; mt < 8; ++mt) {
                vacc[cc][mt] = zacc;
                int mrow = (ck0 + cc) * 128 + mt * 16 + c15;
                int sw = ((mrow >> 2) & 7) << 4;
                #pragma unroll
                for (int ks = 0; ks < 4; ++ks) {
                    bf16x8 bf = *(const bf16x8*)(smem + ((mrow * 256 + ks * 64 + g * 16) ^ sw));
                    vacc[cc][mt] = MFMA16(wvf[ks], bf, vacc[cc][mt]);
                }
            }
        __syncthreads();   // all blkT reads (P1,P2,P3) done everywhere
        #pragma unroll
        for (int cc = 0; cc < 2; ++cc)
            #pragma unroll
            for (int mt = 0; mt < 8; ++mt)
                #pragma unroll
                for (int r = 0; r < 4; ++r) {
                    int c_out = (wv & 7) * 16 + g * 4 + r;
                    int mkl = mt * 16 + c15;
                    *(unsigned short*)(smem + (ck0 + cc) * 32768 + c_out * 256 +
                                       ((2 * mkl) ^ ((c_out & 7) << 4))) = f2bf(vacc[cc][mt][r]);
                }
    }
    __syncthreads();   // B3: Vhat + Khat visible

    // epilogue prefetch (ALL threads): 16 residual reads; complete during P4.
    const int q128 = tid & 127;
    const int h8 = tid >> 7;                        // 0..7 -> 16 channels each
    float xv[16];
    int go_e;
    {
        int nq_e = qq * 128 + q128;
        int vox_e = ((nq_e >> 6) << 12) + (((nq_e >> 3) & 7) << 6) + (nq_e & 7);
        go_e = vbase + vox_e;
        #pragma unroll
        for (int i = 0; i < 16; ++i)
            xv[i] = out[(h8 * 16 + i) * 262144 + go_e];   // = x (memcpy'd), hot
    }

    // P4: barrier-free key-tile loop (waves 0..7). O[16q][128c] per wave.
    if (wv < 8) {
        f32x4 o[8];
        #pragma unroll
        for (int ci = 0; ci < 8; ++ci) o[ci] = zacc;
        float lsum = 0.f;

        for (int kt = 0; kt < 16; ++kt) {
            int mk0 = kt * 32;
            bf16x8 ka[2];
            #pragma unroll
            for (int ki = 0; ki < 2; ++ki) {
                bf16x8 v = zfrag;
                if (g < 2) v = *(const bf16x8*)(smem + KOFF + (mk0 + ki * 16 + c15) * 32 + g * 16);
                ka[ki] = v;
            }

            f32x4 s0 = MFMA16(ka[0], qf, zacc);
            f32x4 s1 = MFMA16(ka[1], qf, zacc);
            float e00 = __expf(s0[0]), e01 = __expf(s0[1]), e02 = __expf(s0[2]), e03 = __expf(s0[3]);
            float e10 = __expf(s1[0]), e11 = __expf(s1[1]), e12 = __expf(s1[2]), e13 = __expf(s1[3]);
            lsum += (e00 + e01) + (e02 + e03) + ((e10 + e11) + (e12 + e13));
            int wA0 = pkbf(e00, e01), wB0 = pkbf(e02, e03);
            int wA1 = pkbf(e10, e11), wB1 = pkbf(e12, e13);
            int src1 = ((2 * g) & 3) * 16 + c15;
            int src2 = ((2 * g + 1) & 3) * 16 + c15;
            int sA0a = __shfl(wA0, src1, 64), sA1a = __shfl(wA1, src1, 64);
            int sB0a = __shfl(wB0, src1, 64), sB1a = __shfl(wB1, src1, 64);
            int sA0b = __shfl(wA0, src2, 64), sA1b = __shfl(wA1, src2, 64);
            int sB0b = __shfl(wB0, src2, 64), sB1b = __shfl(wB1, src2, 64);
            bool k1 = (g >= 2);
            i32x4 uu = { k1 ? sA1a : sA0a, k1 ? sB1a : sB0a,
                         k1 ? sA1b : sA0b, k1 ? sB1b : sB0b };
            bf16x8 pa = __builtin_bit_cast(bf16x8, uu);

            int ckbase = (mk0 >> 7) * 32768;
            int mklb = (2 * (mk0 & 127)) + 16 * g;
            #pragma unroll
            for (int ci = 0; ci < 8; ++ci) {
                int c = ci * 16 + c15;
                bf16x8 vb = *(const bf16x8*)(smem + ckbase + c * 256 + (mklb ^ ((c & 7) << 4)));
                o[ci] = MFMA16(pa, vb, o[ci]);
            }
        }

        // softmax denominators for this wave's 16 queries
        {
            float l = lsum;
            l += __shfl_xor(l, 16, 64);
            l += __shfl_xor(l, 32, 64);
            if (g == 0)
                *(float*)(smem + LOFF + (wv * 16 + c15) * 4) = l;
        }

        __syncthreads();   // B4: Vhat/Khat reads done, safe to overwrite with O

        #pragma unroll
        for (int ci = 0; ci < 8; ++ci)
            #pragma unroll
            for (int r = 0; r < 4; ++r) {
                int nql = wv * 16 + g * 4 + r;       // 0..127
                int c = ci * 16 + c15;
                *(unsigned short*)(smem + c * 256 + ((2 * nql) ^ ((c & 7) << 4))) = f2bf(o[ci][r]);
            }
        __syncthreads();   // B5: O visible
    } else {
        __syncthreads();   // B4
        __syncthreads();   // B5
    }

    // epilogue (ALL 16 waves, 16 channels/thread): out = gamma*(O/l+bv) + x
    {
        float gma = gamma[0];
        float invl = 1.0f / *(const float*)(smem + LOFF + q128 * 4);
        #pragma unroll
        for (int i = 0; i < 16; ++i) {
            int c = h8 * 16 + i;
            float ov = bf2f(*(const unsigned short*)(smem + c * 256 + ((2 * q128) ^ ((c & 7) << 4))));
            out[c * 262144 + go_e] = gma * (ov * invl + bv[c]) + xv[i];
        }
    }
}

extern "C" void kernel_launch(void* const* d_in, const int* in_sizes, int n_in,
                              void* d_out, int out_size, void* d_ws, size_t ws_size,
                              hipStream_t stream) {
    const float* x     = (const float*)d_in[0];
    const float* Wq    = (const float*)d_in[1];
    const float* bq    = (const float*)d_in[2];
    const float* Wk    = (const float*)d_in[3];
    const float* bk    = (const float*)d_in[4];
    const float* Wv    = (const float*)d_in[5];
    const float* bv    = (const float*)d_in[6];
    const float* gamma = (const float*)d_in[7];
    float* out = (float*)d_out;
    (void)in_sizes; (void)n_in; (void)out_size; (void)d_ws; (void)ws_size;

    // 1) SDMA copy: out = x everywhere (diagonal stale, overwritten below).
    hipMemcpyAsync(out, x, (size_t)out_size * sizeof(float),
                   hipMemcpyDeviceToDevice, stream);
    // 2) Wave-specialized diagonal attention (r14 base + 16-wave P3/epilogue).
    battn_kernel<<<dim3(256), dim3(1024), 0, stream>>>(x, Wq, bq, Wk, bk, Wv, bv, gamma, out);
}